// Round 3
// baseline (7997.155 us; speedup 1.0000x reference)
//
#include <hip/hip_runtime.h>
#include <math.h>

// Problem constants (B=16, T=2000, E=1024, K=2048)
#define N_ROWS 32000
#define DIM    1024
#define NCENT  2048
#define ROWS   16       // x rows per block
#define KLANES 16       // centroid lanes per row
#define KU     8        // centroids per lane per outer pass
#define XS_STRIDE 1028  // DIM + 4 pad

// Single self-contained kernel: no d_ws, no inter-kernel dependency.
// Block = 256 threads = 16 rows x 16 centroid-lanes. t: r = t&15, kl = t>>4.
// Lane kl owns centroids k ≡ kl (mod 16), scanned ascending (tie -> lowest k).
// d_k = ||c_k||^2 - 2 x.c_k (matches ref formula); norms computed in-block:
// each r-lane accumulates the j ≡ r (mod 16) slice, then shfl_xor-reduced
// across the 16 consecutive r-lanes of the wave.
__global__ void __launch_bounds__(256, 2) kmeans_argmin_kernel(
    const float* __restrict__ x, const float* __restrict__ cent,
    int* __restrict__ out) {
  __shared__ __align__(16) float xs[ROWS][XS_STRIDE];
  __shared__ float sdist[ROWS][KLANES + 1];
  __shared__ int   sidx[ROWS][KLANES + 1];

  const int t  = threadIdx.x;
  const int r  = t & (ROWS - 1);
  const int kl = t >> 4;  // 0..15
  const size_t row0 = (size_t)blockIdx.x * ROWS;

  // Stage 16 rows of x into LDS (float4, coalesced).
  for (int i = t; i < ROWS * (DIM / 4); i += 256) {
    const int rr = i >> 8;     // DIM/4 = 256 float4 per row
    const int jj = i & 255;
    float4 v = ((const float4*)(x + (row0 + rr) * (size_t)DIM))[jj];
    *(float4*)&xs[rr][jj * 4] = v;
  }
  __syncthreads();

  float best = INFINITY;
  int   bidx = 0;

  for (int mo = 0; mo < NCENT / KLANES / KU; ++mo) {  // 16 outer passes
    const int kbase = kl + KLANES * (mo * KU);        // k_i = kbase + 16*i
    const float4* crow[KU];
#pragma unroll
    for (int i = 0; i < KU; ++i)
      crow[i] = (const float4*)(cent + (size_t)(kbase + KLANES * i) * DIM);

    float acc[KU], nrm[KU];
#pragma unroll
    for (int i = 0; i < KU; ++i) { acc[i] = 0.f; nrm[i] = 0.f; }

    for (int jo = 0; jo < 16; ++jo) {
#pragma unroll 4
      for (int jj = 0; jj < 16; ++jj) {
        const int j = jo * 16 + jj;
        const float4 xv = *(const float4*)&xs[r][j * 4];
#pragma unroll
        for (int i = 0; i < KU; ++i) {
          const float4 cv = crow[i][j];
          acc[i] = fmaf(cv.x, xv.x, acc[i]);
          acc[i] = fmaf(cv.y, xv.y, acc[i]);
          acc[i] = fmaf(cv.z, xv.z, acc[i]);
          acc[i] = fmaf(cv.w, xv.w, acc[i]);
        }
      }
      // Norm partial for this lane's j-slice (j = jo*16 + r), coalesced loads.
      const int jn = jo * 16 + r;
#pragma unroll
      for (int i = 0; i < KU; ++i) {
        const float4 cn = crow[i][jn];
        nrm[i] = fmaf(cn.x, cn.x, nrm[i]);
        nrm[i] = fmaf(cn.y, cn.y, nrm[i]);
        nrm[i] = fmaf(cn.z, cn.z, nrm[i]);
        nrm[i] = fmaf(cn.w, cn.w, nrm[i]);
      }
    }

    // Reduce norms across the 16 r-lanes (consecutive lanes within the wave;
    // xor masks 1,2,4,8 stay inside the 16-lane group), then update argmin.
#pragma unroll
    for (int i = 0; i < KU; ++i) {
      float n = nrm[i];
      n += __shfl_xor(n, 1, 64);
      n += __shfl_xor(n, 2, 64);
      n += __shfl_xor(n, 4, 64);
      n += __shfl_xor(n, 8, 64);
      const float d = fmaf(-2.f, acc[i], n);
      const int k = kbase + KLANES * i;
      if (d < best) { best = d; bidx = k; }  // strict <: keep lowest k
    }
  }

  sdist[r][kl] = best;
  sidx[r][kl]  = bidx;
  __syncthreads();

  // Per-row lexicographic (dist, idx) reduce over the 16 kl-lanes.
  if (kl == 0) {
    float bb = sdist[r][0];
    int   bi = sidx[r][0];
#pragma unroll
    for (int i = 1; i < KLANES; ++i) {
      const float d  = sdist[r][i];
      const int   ix = sidx[r][i];
      if (d < bb || (d == bb && ix < bi)) { bb = d; bi = ix; }
    }
    out[row0 + r] = bi;  // int64 ref -> harness reads int32
  }
}

extern "C" void kernel_launch(void* const* d_in, const int* in_sizes, int n_in,
                              void* d_out, int out_size, void* d_ws, size_t ws_size,
                              hipStream_t stream) {
  const float* x    = (const float*)d_in[0];   // [16,2000,1024] fp32
  const float* cent = (const float*)d_in[1];   // [2048,1024] fp32
  int* out = (int*)d_out;                      // 32000 int32 indices
  (void)d_ws; (void)ws_size;                   // deliberately unused (R2 post-mortem)

  hipLaunchKernelGGL(kmeans_argmin_kernel, dim3(N_ROWS / ROWS), dim3(256), 0,
                     stream, x, cent, out);
}

// Round 5
// 1130.020 us; speedup vs baseline: 7.0770x; 7.0770x over previous
//
#include <hip/hip_runtime.h>
#include <math.h>

// Problem constants (B=16, T=2000, E=1024, K=2048)
#define N_ROWS 32000
#define DIM    1024
#define NCENT  2048
#define MROWS  64            // x rows per block
#define NKP    256           // centroids per k-pass
#define KE     32            // e per staged chunk
#define NPASS  (NCENT / NKP) // 8
#define NCHUNK (DIM / KE)    // 32
#define TAU    0.015625f     // rescore margin (1/64, ~60 sigma of f16-split error)
#define CS_KK  257           // 256 + 1 pad row (breaks staging write conflicts)
#define XS_KK  65            // 64 + 1 pad row

typedef _Float16 half4v __attribute__((ext_vector_type(4)));
typedef _Float16 half8v __attribute__((ext_vector_type(8)));
typedef float    floatx16 __attribute__((ext_vector_type(16)));

// Split a float4 into hi/lo f16 halves (RNE). Scalar temps -> vector element
// assignment (non-const refs can't bind to ext_vector elements).
__device__ __forceinline__ void split4_f16(const float4 v, half4v& h, half4v& l) {
  const float f[4] = {v.x, v.y, v.z, v.w};
#pragma unroll
  for (int c = 0; c < 4; ++c) {
    const _Float16 hh = (_Float16)f[c];
    h[c] = hh;
    l[c] = (_Float16)(f[c] - (float)hh);
  }
}

// Layouts:
//  cs[part][esub][kk][j] : centroid tile, part 0=hi 1=lo, esub=(e within chunk)>>3,
//                          kk = k within pass, j = e&7.  A-frag = 8 contiguous f16.
//  xs[part][esub][row][j]: x tile, same scheme.          B-frag = 8 contiguous f16.
// mfma_f32_32x32x16_f16: A[m=lane&31][e=(lane>>5)*8+j], B[e=(lane>>5)*8+j][n=lane&31],
// D: col(n)=lane&31, row(m)=(reg&3)+8*(reg>>2)+4*(lane>>5)  [guide §3, m74/m101].
__global__ void __launch_bounds__(256, 2) kmeans_mfma_kernel(
    const float* __restrict__ x, const float* __restrict__ cent,
    int* __restrict__ out) {
  __shared__ __align__(16) _Float16 cs[2][4][CS_KK][8];  // 32,896 B
  __shared__ __align__(16) _Float16 xs[2][4][XS_KK][8];  //  8,320 B
  __shared__ float nrm[NKP];
  __shared__ float sbest[MROWS][4];
  __shared__ float sbest2[MROWS][4];
  __shared__ int   sbidx[MROWS][4];
  __shared__ int   sres[MROWS];
  __shared__ int   sflag[MROWS];
  __shared__ float p2d[4];
  __shared__ int   p2k[4];

  const int t    = threadIdx.x;
  const int lane = t & 63;
  const int w    = t >> 6;      // wave 0..3 -> k-quarter within pass
  const int l31  = lane & 31;
  const int lhi  = lane >> 5;   // 0/1
  const size_t row0 = (size_t)blockIdx.x * MROWS;

  float best[2]  = {INFINITY, INFINITY};
  float best2[2] = {INFINITY, INFINITY};
  int   bidx[2]  = {0, 0};

  for (int p = 0; p < NPASS; ++p) {
    const int kbase = p * NKP;
    floatx16 acc[2][2] = {};   // [kt][nt]
    float nacc[8] = {};        // per-thread centroid-norm partials

    for (int ec = 0; ec < NCHUNK; ++ec) {
      const int ebase = ec * KE;
      __syncthreads();  // previous chunk's LDS reads complete before overwrite

      // Stage x: 64 rows x 32 e = 512 float4.
#pragma unroll
      for (int i = 0; i < 2; ++i) {
        const int idx = t + 256 * i;
        const int row = idx >> 3, e4 = idx & 7;
        const float4 v = *(const float4*)(x + (row0 + row) * DIM + ebase + 4 * e4);
        half4v h, l;
        split4_f16(v, h, l);
        *(half4v*)&xs[0][e4 >> 1][row][(e4 & 1) * 4] = h;
        *(half4v*)&xs[1][e4 >> 1][row][(e4 & 1) * 4] = l;
      }
      // Stage C: 256 k x 32 e = 2048 float4; thread t owns k in {(t>>3)+32i},
      // accumulating exact fp32 norm partials from in-register values.
#pragma unroll
      for (int i = 0; i < 8; ++i) {
        const int idx = t + 256 * i;
        const int kk = idx >> 3, e4 = idx & 7;
        const float4 v =
            *(const float4*)(cent + (size_t)(kbase + kk) * DIM + ebase + 4 * e4);
        nacc[i] = fmaf(v.x, v.x, nacc[i]); nacc[i] = fmaf(v.y, v.y, nacc[i]);
        nacc[i] = fmaf(v.z, v.z, nacc[i]); nacc[i] = fmaf(v.w, v.w, nacc[i]);
        half4v h, l;
        split4_f16(v, h, l);
        *(half4v*)&cs[0][e4 >> 1][kk][(e4 & 1) * 4] = h;
        *(half4v*)&cs[1][e4 >> 1][kk][(e4 & 1) * 4] = l;
      }
      __syncthreads();

      // MFMA: 2 e-steps of 16; wave w covers k-quarter w*64 (2 kt-subtiles),
      // both 32-row n-subtiles. 3 split terms (h*h + h*l + l*h).
#pragma unroll
      for (int es = 0; es < 2; ++es) {
        const int esub = es * 2 + lhi;
        half8v Ah[2], Al[2], Bh[2], Bl[2];
#pragma unroll
        for (int kt = 0; kt < 2; ++kt) {
          const int kk = w * 64 + kt * 32 + l31;
          Ah[kt] = *(const half8v*)&cs[0][esub][kk][0];
          Al[kt] = *(const half8v*)&cs[1][esub][kk][0];
        }
#pragma unroll
        for (int nt = 0; nt < 2; ++nt) {
          const int rr = nt * 32 + l31;
          Bh[nt] = *(const half8v*)&xs[0][esub][rr][0];
          Bl[nt] = *(const half8v*)&xs[1][esub][rr][0];
        }
#pragma unroll
        for (int kt = 0; kt < 2; ++kt)
#pragma unroll
          for (int nt = 0; nt < 2; ++nt) {
            acc[kt][nt] = __builtin_amdgcn_mfma_f32_32x32x16_f16(
                Ah[kt], Bh[nt], acc[kt][nt], 0, 0, 0);
            acc[kt][nt] = __builtin_amdgcn_mfma_f32_32x32x16_f16(
                Ah[kt], Bl[nt], acc[kt][nt], 0, 0, 0);
            acc[kt][nt] = __builtin_amdgcn_mfma_f32_32x32x16_f16(
                Al[kt], Bh[nt], acc[kt][nt], 0, 0, 0);
          }
      }
    }

    // Reduce norm partials: k's 8 owner threads are 8 consecutive lanes.
#pragma unroll
    for (int i = 0; i < 8; ++i) {
      float n = nacc[i];
      n += __shfl_xor(n, 1, 64);
      n += __shfl_xor(n, 2, 64);
      n += __shfl_xor(n, 4, 64);
      if ((t & 7) == 0) nrm[(t >> 3) + 32 * i] = n;
    }
    __syncthreads();

    // Argmin update: d = nrm[k] - 2*dot. Ties land in the tau-flag -> exact rescore.
#pragma unroll
    for (int kt = 0; kt < 2; ++kt) {
      const int kmb = w * 64 + kt * 32 + 4 * lhi;
#pragma unroll
      for (int r = 0; r < 16; ++r) {
        const int km = kmb + (r & 3) + 8 * (r >> 2);
        const float nk = nrm[km];
        const int kg = kbase + km;
#pragma unroll
        for (int nt = 0; nt < 2; ++nt) {
          const float d = fmaf(-2.0f, acc[kt][nt][r], nk);
          if (d < best[nt]) { best2[nt] = best[nt]; best[nt] = d; bidx[nt] = kg; }
          else best2[nt] = fminf(best2[nt], d);
        }
      }
    }
  }

  // Merge lane halves (l, l^32) then write per-wave row candidates.
#pragma unroll
  for (int nt = 0; nt < 2; ++nt) {
    float b = best[nt], b2 = best2[nt];
    int bi = bidx[nt];
    const float ob  = __shfl_xor(b, 32, 64);
    const float ob2 = __shfl_xor(b2, 32, 64);
    const int   obi = __shfl_xor(bi, 32, 64);
    const float nb2 = fminf(fminf(b2, ob2), fmaxf(b, ob));
    if (ob < b || (ob == b && obi < bi)) { b = ob; bi = obi; }
    if (lhi == 0) {
      const int row = nt * 32 + l31;
      sbest[row][w] = b; sbest2[row][w] = nb2; sbidx[row][w] = bi;
    }
  }
  __syncthreads();

  if (t < MROWS) {
    float b = sbest[t][0], b2 = sbest2[t][0];
    int bi = sbidx[t][0];
#pragma unroll
    for (int ww = 1; ww < 4; ++ww) {
      const float cb = sbest[t][ww], cb2 = sbest2[t][ww];
      const int cbi = sbidx[t][ww];
      const float nb2 = fminf(fminf(b2, cb2), fmaxf(b, cb));
      if (cb < b || (cb == b && cbi < bi)) { b = cb; bi = cbi; }
      b2 = nb2;
    }
    sres[t] = bi;
    sflag[t] = (b2 - b < TAU) ? 1 : 0;
  }
  __syncthreads();

  // Phase 2: exact fp32 rescore of flagged rows (expected ~0-1 per ~50 blocks).
  float* xrow = (float*)&xs[0][0][0][0];  // 4 KB fp32 scratch, reuses xs
  for (int r = 0; r < MROWS; ++r) {
    if (sflag[r]) {               // uniform branch (same LDS word for all threads)
      __syncthreads();
      for (int i = t; i < DIM / 4; i += 256)
        ((float4*)xrow)[i] = *(const float4*)(x + (row0 + r) * DIM + 4 * i);
      __syncthreads();
      float bd = INFINITY; int bk = NCENT;
      for (int i = 0; i < NCENT / 256; ++i) {
        const int k = t + 256 * i;
        const float4* crow = (const float4*)(cent + (size_t)k * DIM);
        float a0 = 0.f, a1 = 0.f, a2 = 0.f, a3 = 0.f;
        float n0 = 0.f, n1 = 0.f, n2 = 0.f, n3 = 0.f;
#pragma unroll 8
        for (int j = 0; j < DIM / 4; ++j) {
          const float4 cv = crow[j];
          const float4 xv = ((const float4*)xrow)[j];
          a0 = fmaf(cv.x, xv.x, a0); n0 = fmaf(cv.x, cv.x, n0);
          a1 = fmaf(cv.y, xv.y, a1); n1 = fmaf(cv.y, cv.y, n1);
          a2 = fmaf(cv.z, xv.z, a2); n2 = fmaf(cv.z, cv.z, n2);
          a3 = fmaf(cv.w, xv.w, a3); n3 = fmaf(cv.w, cv.w, n3);
        }
        const float d = fmaf(-2.f, (a0 + a1) + (a2 + a3), (n0 + n1) + (n2 + n3));
        if (d < bd || (d == bd && k < bk)) { bd = d; bk = k; }
      }
#pragma unroll
      for (int off = 32; off > 0; off >>= 1) {
        const float od = __shfl_down(bd, off, 64);
        const int   ok = __shfl_down(bk, off, 64);
        if (od < bd || (od == bd && ok < bk)) { bd = od; bk = ok; }
      }
      if (lane == 0) { p2d[w] = bd; p2k[w] = bk; }
      __syncthreads();
      if (t == 0) {
        float fd = p2d[0]; int fk = p2k[0];
#pragma unroll
        for (int ww = 1; ww < 4; ++ww) {
          if (p2d[ww] < fd || (p2d[ww] == fd && p2k[ww] < fk)) {
            fd = p2d[ww]; fk = p2k[ww];
          }
        }
        sres[r] = fk;
      }
      __syncthreads();
    }
  }
  __syncthreads();

  if (t < MROWS) out[row0 + t] = sres[t];
}

extern "C" void kernel_launch(void* const* d_in, const int* in_sizes, int n_in,
                              void* d_out, int out_size, void* d_ws, size_t ws_size,
                              hipStream_t stream) {
  const float* x    = (const float*)d_in[0];   // [16,2000,1024] fp32
  const float* cent = (const float*)d_in[1];   // [2048,1024] fp32
  int* out = (int*)d_out;                      // 32000 int32 indices
  (void)d_ws; (void)ws_size;                   // unused (R2 post-mortem)

  hipLaunchKernelGGL(kmeans_mfma_kernel, dim3(N_ROWS / MROWS), dim3(256), 0,
                     stream, x, cent, out);
}